// Round 1
// baseline (363.035 us; speedup 1.0000x reference)
//
#include <hip/hip_runtime.h>

#define BB 4096
#define TT 512
#define HH 32

__device__ __forceinline__ float fast_tanh(float v) {
    // tanh(x) = 1 - 2/(exp(2x)+1); v_exp + v_rcp, ~1e-7 abs error
    float e = __expf(2.0f * v);
    float r = __builtin_amdgcn_rcpf(e + 1.0f);
    return fmaf(-2.0f, r, 1.0f);
}

__global__ __launch_bounds__(256) void rnn2_kernel(
    const float* __restrict__ x,      // [B, T]
    const float* __restrict__ hstate, // [2, B, H]
    const float* __restrict__ Wih0,   // [H, 1]
    const float* __restrict__ Whh0,   // [H, H]
    const float* __restrict__ bih0,   // [H]
    const float* __restrict__ bhh0,   // [H]
    const float* __restrict__ Wih1,   // [H, H]
    const float* __restrict__ Whh1,   // [H, H]
    const float* __restrict__ bih1,   // [H]
    const float* __restrict__ bhh1,   // [H]
    const float* __restrict__ Wfc,    // [1, H]
    const float* __restrict__ bfc,    // [1]
    float* __restrict__ out)          // [B] pred ++ [2,B,H] h_new
{
    __shared__ float hs0[8][32];
    __shared__ float hs1[8][32];

    const int tid = threadIdx.x;
    const int hp  = tid & 31;   // which h row this lane produces
    const int bs  = tid >> 5;   // batch slot within block (0..7); wave = 2 slots
    const int b   = blockIdx.x * 8 + bs;

    // ---- per-lane weights in registers (96 VGPRs) ----
    float4 w0[8], wi1[8], w1[8];
    const float4* Whh0v = (const float4*)(Whh0 + hp * HH);
    const float4* Wih1v = (const float4*)(Wih1 + hp * HH);
    const float4* Whh1v = (const float4*)(Whh1 + hp * HH);
#pragma unroll
    for (int j = 0; j < 8; ++j) {
        w0[j]  = Whh0v[j];
        wi1[j] = Wih1v[j];
        w1[j]  = Whh1v[j];
    }
    const float wx = Wih0[hp];
    const float b0 = bih0[hp] + bhh0[hp];
    const float b1 = bih1[hp] + bhh1[hp];

    // ---- init state ----
    float h0n = hstate[b * HH + hp];
    float h1n = hstate[BB * HH + b * HH + hp];
    hs0[bs][hp] = h0n;
    hs1[bs][hp] = h1n;

    const float4* x4   = (const float4*)(x + b * TT);
    const float4* hs0v = (const float4*)(&hs0[bs][0]);
    const float4* hs1v = (const float4*)(&hs1[bs][0]);

    float4 xv = x4[0];

    for (int t4 = 0; t4 < TT / 4; ++t4) {
        float4 xn = x4[(t4 < TT / 4 - 1) ? (t4 + 1) : t4];  // prefetch
#pragma unroll
        for (int j = 0; j < 4; ++j) {
            const float xt = (j == 0) ? xv.x : (j == 1) ? xv.y : (j == 2) ? xv.z : xv.w;

            // ---- layer 0: a0 = b0 + wx*x + Whh0[hp,:] . h0 ----
            float sx = fmaf(wx, xt, b0), sy = 0.f, sz = 0.f, sw = 0.f;
#pragma unroll
            for (int k = 0; k < 8; ++k) {
                float4 hv = hs0v[k];  // broadcast read (same addr across 32 lanes)
                sx = fmaf(w0[k].x, hv.x, sx);
                sy = fmaf(w0[k].y, hv.y, sy);
                sz = fmaf(w0[k].z, hv.z, sz);
                sw = fmaf(w0[k].w, hv.w, sw);
            }
            h0n = fast_tanh((sx + sy) + (sz + sw));
            hs0[bs][hp] = h0n;  // publish new h0 (wave-synchronous)

            // ---- layer 1: a1 = b1 + Wih1[hp,:] . h0new + Whh1[hp,:] . h1 ----
            float p0 = b1, p1 = 0.f, p2 = 0.f, p3 = 0.f;
#pragma unroll
            for (int k = 0; k < 8; ++k) {
                float4 u = hs0v[k];  // new h0
                float4 v = hs1v[k];  // old h1
                p0 = fmaf(wi1[k].x, u.x, p0);
                p1 = fmaf(wi1[k].y, u.y, p1);
                p2 = fmaf(wi1[k].z, u.z, p2);
                p3 = fmaf(wi1[k].w, u.w, p3);
                p0 = fmaf(w1[k].x, v.x, p0);
                p1 = fmaf(w1[k].y, v.y, p1);
                p2 = fmaf(w1[k].z, v.z, p2);
                p3 = fmaf(w1[k].w, v.w, p3);
            }
            h1n = fast_tanh((p0 + p1) + (p2 + p3));
            hs1[bs][hp] = h1n;  // publish new h1 (all lanes read old h1 above first)
        }
        xv = xn;
    }

    // ---- epilogue ----
    // pred[b] = Wfc . h1_last + bfc
    float p = Wfc[hp] * h1n;
#pragma unroll
    for (int off = 16; off > 0; off >>= 1) p += __shfl_xor(p, off, 32);
    if (hp == 0) out[b] = p + bfc[0];

    // h_new [2, B, H]
    out[BB + b * HH + hp]           = h0n;
    out[BB + BB * HH + b * HH + hp] = h1n;
}

extern "C" void kernel_launch(void* const* d_in, const int* in_sizes, int n_in,
                              void* d_out, int out_size, void* d_ws, size_t ws_size,
                              hipStream_t stream) {
    const float* x      = (const float*)d_in[0];
    const float* hstate = (const float*)d_in[1];
    const float* Wih0   = (const float*)d_in[2];
    const float* Whh0   = (const float*)d_in[3];
    const float* bih0   = (const float*)d_in[4];
    const float* bhh0   = (const float*)d_in[5];
    const float* Wih1   = (const float*)d_in[6];
    const float* Whh1   = (const float*)d_in[7];
    const float* bih1   = (const float*)d_in[8];
    const float* bhh1   = (const float*)d_in[9];
    const float* Wfc    = (const float*)d_in[10];
    const float* bfc    = (const float*)d_in[11];
    float* out = (float*)d_out;

    dim3 grid(BB / 8);   // 512 blocks, 8 batches each
    dim3 block(256);
    hipLaunchKernelGGL(rnn2_kernel, grid, block, 0, stream,
                       x, hstate, Wih0, Whh0, bih0, bhh0,
                       Wih1, Whh1, bih1, bhh1, Wfc, bfc, out);
}

// Round 3
// 223.702 us; speedup vs baseline: 1.6228x; 1.6228x over previous
//
#include <hip/hip_runtime.h>
#include <hip/hip_bf16.h>

#define BB 4096
#define TT 512
#define HH 32

typedef __attribute__((ext_vector_type(8))) short short8;   // 8 x bf16 (4 VGPRs)
typedef __attribute__((ext_vector_type(4))) float f32x4;    // MFMA C/D

#define MFMA16 __builtin_amdgcn_mfma_f32_16x16x32_bf16
#define EXP2F  __builtin_amdgcn_exp2f   // v_exp_f32 (computes 2^x)

union frag_u { short8 s8; __hip_bfloat162 b2[4]; };

// Computes D = W @ H^T per step with M = h'-rows (2 tiles of 16), N = 16 batches.
// Row permutation pi_t(m) = 8*(m>>2) + (m&3) + 4t makes the C/D output layout
// (lane: col=l&15, rows 4q+r) equal to the B-operand layout of the next matvec
// (lane: n=l&15, k=8q+j, j=4t+r)  ->  recurrence stays entirely in registers.
// Weights/biases pre-scaled by 2*log2(e): tanh(v) = 1 - 2/(exp2(sc*v)+1).
__global__ __launch_bounds__(64) void rnn2_mfma(
    const float* __restrict__ x,      // [B, T]
    const float* __restrict__ hstate, // [2, B, H]
    const float* __restrict__ Wih0,   // [H, 1]
    const float* __restrict__ Whh0,   // [H, H]
    const float* __restrict__ bih0,   // [H]
    const float* __restrict__ bhh0,   // [H]
    const float* __restrict__ Wih1,   // [H, H]
    const float* __restrict__ Whh1,   // [H, H]
    const float* __restrict__ bih1,   // [H]
    const float* __restrict__ bhh1,   // [H]
    const float* __restrict__ Wfc,    // [1, H]
    const float* __restrict__ bfc,    // [1]
    float* __restrict__ out)          // [B] pred ++ [2,B,H] h_new
{
    const int l = threadIdx.x;   // 0..63
    const int q = l >> 4;        // lane quad -> k-offset 8q
    const int n = l & 15;        // batch-in-tile / matrix row m
    const int b = blockIdx.x * 16 + n;

    const float SC = 2.8853900817779268f;  // 2*log2(e)

    // ---- weight A-fragments (bf16, scaled), permuted rows ----
    const int r0 = 8 * (n >> 2) + (n & 3);
    short8 A0[2], A1i[2], A1h[2];
#pragma unroll
    for (int t = 0; t < 2; ++t) {
        const int row = r0 + 4 * t;
        const float* p0 = Whh0 + row * HH + q * 8;
        const float* p1 = Wih1 + row * HH + q * 8;
        const float* p2 = Whh1 + row * HH + q * 8;
        frag_u f0, f1, f2;
#pragma unroll
        for (int jj = 0; jj < 4; ++jj) {
            f0.b2[jj] = __float22bfloat162_rn(float2{SC * p0[2 * jj], SC * p0[2 * jj + 1]});
            f1.b2[jj] = __float22bfloat162_rn(float2{SC * p1[2 * jj], SC * p1[2 * jj + 1]});
            f2.b2[jj] = __float22bfloat162_rn(float2{SC * p2[2 * jj], SC * p2[2 * jj + 1]});
        }
        A0[t] = f0.s8; A1i[t] = f1.s8; A1h[t] = f2.s8;
    }

    // ---- per-lane constants over j=0..7  (h' = 8q + j) ----
    float wxs[8], b0s[8], b1s[8], wfc8[8];
#pragma unroll
    for (int j = 0; j < 8; ++j) {
        const int hh = 8 * q + j;
        wxs[j]  = SC * Wih0[hh];
        b0s[j]  = SC * (bih0[hh] + bhh0[hh]);
        b1s[j]  = SC * (bih1[hh] + bhh1[hh]);
        wfc8[j] = Wfc[hh];
    }
    f32x4 c1t0, c1t1;
#pragma unroll
    for (int r = 0; r < 4; ++r) { c1t0[r] = b1s[r]; c1t1[r] = b1s[4 + r]; }

    // ---- initial h state as B-fragments ----
    frag_u h0f, h1f;
    {
        const float* p0 = hstate + b * HH + 8 * q;
        const float* p1 = hstate + BB * HH + b * HH + 8 * q;
#pragma unroll
        for (int jj = 0; jj < 4; ++jj) {
            h0f.b2[jj] = __float22bfloat162_rn(float2{p0[2 * jj], p0[2 * jj + 1]});
            h1f.b2[jj] = __float22bfloat162_rn(float2{p1[2 * jj], p1[2 * jj + 1]});
        }
    }
    short8 hb0 = h0f.s8, hb1 = h1f.s8;

    float hf0[8], hf1[8];

    const float4* xp = (const float4*)(x + (size_t)b * TT);
    float4 xv = xp[0];

    for (int t4 = 0; t4 < TT / 4; ++t4) {
        float4 xn = xp[(t4 < TT / 4 - 1) ? t4 + 1 : t4];  // prefetch
#pragma unroll
        for (int jj = 0; jj < 4; ++jj) {
            const float xt = (jj == 0) ? xv.x : (jj == 1) ? xv.y : (jj == 2) ? xv.z : xv.w;

            // early (off critical path): Db = SC*Whh1 . h1_old + bias1
            f32x4 db0 = MFMA16(A1h[0], hb1, c1t0, 0, 0, 0);
            f32x4 db1 = MFMA16(A1h[1], hb1, c1t1, 0, 0, 0);

            // layer 0: C = SC*(bias0 + wx*x_t), D += SC*Whh0 . h0_old
            f32x4 c00, c01;
#pragma unroll
            for (int r = 0; r < 4; ++r) {
                c00[r] = fmaf(wxs[r], xt, b0s[r]);
                c01[r] = fmaf(wxs[4 + r], xt, b0s[4 + r]);
            }
            f32x4 d00 = MFMA16(A0[0], hb0, c00, 0, 0, 0);
            f32x4 d01 = MFMA16(A0[1], hb0, c01, 0, 0, 0);

            frag_u nh0;
#pragma unroll
            for (int r = 0; r < 4; ++r) {
                float e0 = EXP2F(d00[r]);
                float e1 = EXP2F(d01[r]);
                hf0[r]     = fmaf(-2.0f, __builtin_amdgcn_rcpf(e0 + 1.0f), 1.0f);
                hf0[4 + r] = fmaf(-2.0f, __builtin_amdgcn_rcpf(e1 + 1.0f), 1.0f);
            }
#pragma unroll
            for (int p2 = 0; p2 < 4; ++p2)
                nh0.b2[p2] = __float22bfloat162_rn(float2{hf0[2 * p2], hf0[2 * p2 + 1]});
            hb0 = nh0.s8;

            // layer 1 finish: D = SC*Wih1 . h0_new + Db
            f32x4 d10 = MFMA16(A1i[0], hb0, db0, 0, 0, 0);
            f32x4 d11 = MFMA16(A1i[1], hb0, db1, 0, 0, 0);

            frag_u nh1;
#pragma unroll
            for (int r = 0; r < 4; ++r) {
                float e0 = EXP2F(d10[r]);
                float e1 = EXP2F(d11[r]);
                hf1[r]     = fmaf(-2.0f, __builtin_amdgcn_rcpf(e0 + 1.0f), 1.0f);
                hf1[4 + r] = fmaf(-2.0f, __builtin_amdgcn_rcpf(e1 + 1.0f), 1.0f);
            }
#pragma unroll
            for (int p2 = 0; p2 < 4; ++p2)
                nh1.b2[p2] = __float22bfloat162_rn(float2{hf1[2 * p2], hf1[2 * p2 + 1]});
            hb1 = nh1.s8;
        }
        xv = xn;
    }

    // ---- epilogue ----
    float p = 0.f;
#pragma unroll
    for (int j = 0; j < 8; ++j) p = fmaf(wfc8[j], hf1[j], p);
    p += __shfl_xor(p, 16);
    p += __shfl_xor(p, 32);
    if (q == 0) out[b] = p + bfc[0];

#pragma unroll
    for (int j = 0; j < 8; ++j) {
        out[BB + b * HH + 8 * q + j]           = hf0[j];
        out[BB + BB * HH + b * HH + 8 * q + j] = hf1[j];
    }
}

extern "C" void kernel_launch(void* const* d_in, const int* in_sizes, int n_in,
                              void* d_out, int out_size, void* d_ws, size_t ws_size,
                              hipStream_t stream) {
    const float* x      = (const float*)d_in[0];
    const float* hstate = (const float*)d_in[1];
    const float* Wih0   = (const float*)d_in[2];
    const float* Whh0   = (const float*)d_in[3];
    const float* bih0   = (const float*)d_in[4];
    const float* bhh0   = (const float*)d_in[5];
    const float* Wih1   = (const float*)d_in[6];
    const float* Whh1   = (const float*)d_in[7];
    const float* bih1   = (const float*)d_in[8];
    const float* bhh1   = (const float*)d_in[9];
    const float* Wfc    = (const float*)d_in[10];
    const float* bfc    = (const float*)d_in[11];
    float* out = (float*)d_out;

    dim3 grid(BB / 16);  // 256 waves, one 16-batch tile each -> 1 wave/CU
    dim3 block(64);
    hipLaunchKernelGGL(rnn2_mfma, grid, block, 0, stream,
                       x, hstate, Wih0, Whh0, bih0, bhh0,
                       Wih1, Whh1, bih1, bhh1, Wfc, bfc, out);
}